// Round 4
// baseline (13030.078 us; speedup 1.0000x reference)
//
#include <hip/hip_runtime.h>
#include <hip/hip_bf16.h>
#include <cstdint>
#include <cstddef>

#define Hh 64
#define Vv 32000
#define Bb 32
#define Tt 512

// ---- ws layout (bytes) ----
#define IP_OFF    0u
#define IP_SZ     ((size_t)Bb*Tt*Hh*4)          // 4 MB   ip[b][t][j]
#define S_OFF     (IP_OFF + IP_SZ)
#define S_SZ      ((size_t)Bb*Tt*4)             // 64 KB  S[b][t]
#define U511_OFF  (S_OFF + S_SZ)
#define U511_SZ   ((size_t)Bb*Hh*Hh*4)          // 512 KB u511[b][j][i]
#define STAGE_OFF (U511_OFF + U511_SZ)
#define STAGE_SZ  ((size_t)Tt*Bb*Hh*Hh*2)       // 128 MB stage[s][b][j][i] bf16

__device__ __forceinline__ float wave_max64(float v){
  #pragma unroll
  for (int off=32; off; off>>=1) v = fmaxf(v, __shfl_xor(v, off, 64));
  return v;
}

// One workgroup per batch chain. 1024 threads = 16 waves.
// thread (w = tid>>6, l = tid&63) owns outputs U[i=l][j=4w+jj], jj=0..3.
// alpha slice held in 256 VGPRs: a[jj][k] = alpha[l][4w+jj][k].
__global__ __launch_bounds__(1024) void sohmm_scan(
    const float* __restrict__ alpha, const float* __restrict__ beta,
    const int* __restrict__ ids, float* __restrict__ out,
    float* __restrict__ ipbuf, float* __restrict__ S_arr,
    float* __restrict__ u511, __hip_bfloat16* __restrict__ stage,
    int use_stage)
{
  const int b   = blockIdx.x;
  const int tid = threadIdx.x;
  const int w   = tid >> 6;     // 0..15
  const int l   = tid & 63;     // = i
  const int j0  = w * 4;

  __shared__ float Zb[2][Hh][68];   // [parity][row=i_prev][col=j_prev], stride 68 (16B-aligned rows)
  __shared__ float wred[2][16];

  // ---- persistent alpha -> 256 VGPRs ----
  float a[4][64];
  {
    #pragma unroll
    for (int jj=0; jj<4; jj++){
      const float4* ap = (const float4*)(alpha + ((size_t)l*Hh + (j0+jj))*Hh);
      #pragma unroll
      for (int k4=0;k4<16;k4++){
        float4 v = ap[k4];
        a[jj][4*k4+0]=v.x; a[jj][4*k4+1]=v.y; a[jj][4*k4+2]=v.z; a[jj][4*k4+3]=v.w;
      }
    }
  }

  // ---- emissions: ip[b][t][j] = beta[j][ids[b][t]] ----
  for (int r=0;r<32;r++){
    int flat = r*1024 + tid;          // 32768 = 512*64
    int t  = flat >> 6;
    int jj = flat & 63;
    int id = ids[b*Tt + t];
    ipbuf[((size_t)b*Tt + t)*Hh + jj] = beta[(size_t)jj*Vv + id];
  }
  __syncthreads();

  // ---- step 0 (t = T-1): u0 = exp(ip[j]) ----
  float S = 0.f;
  {
    float4 ipq = *(const float4*)(ipbuf + ((size_t)b*Tt + (Tt-1))*Hh + j0);
    float u[4] = { __expf(ipq.x), __expf(ipq.y), __expf(ipq.z), __expf(ipq.w) };
    float vm = fmaxf(fmaxf(u[0],u[1]), fmaxf(u[2],u[3]));
    vm = wave_max64(vm);
    if (l==0) wred[0][w] = vm;
    #pragma unroll
    for (int jj=0;jj<4;jj++) Zb[0][l][j0+jj] = u[jj];
    if (tid==0) S_arr[(size_t)b*Tt + 0] = 0.f;
    if (use_stage){
      #pragma unroll
      for (int jj=0;jj<4;jj++)
        stage[((size_t)0*Bb + b)*4096 + (size_t)(j0+jj)*64 + l] = __float2bfloat16(u[jj]);
    } else {
      #pragma unroll
      for (int jj=0;jj<4;jj++)
        out[(((size_t)0*Hh + l)*Hh + (j0+jj))*Bb + b] = __logf(u[jj]);  // == ip
    }
    __syncthreads();
  }

  // ---- steps 1..T-1 ----
  for (int s=1; s<Tt; s++){
    const int pr = (s+1)&1;     // read parity (s-1)
    const int pw = s&1;         // write parity
    const int t  = (Tt-1) - s;

    // prefetch emissions (uniform per wave, one float4)
    float4 ipq = *(const float4*)(ipbuf + ((size_t)b*Tt + t)*Hh + j0);

    // previous-step max
    float mu = wred[pr][0];
    #pragma unroll
    for (int q=1;q<16;q++) mu = fmaxf(mu, wred[pr][q]);
    const float rinv = 1.0f / mu;
    S += __logf(mu);

    // U[i=l][j] = (sum_k a[jj][k] * Z[j][k]) * rinv * exp(ip[j])
    float u[4];
    #pragma unroll
    for (int jj=0;jj<4;jj++){
      const float* zrow = &Zb[pr][j0+jj][0];
      float acc = 0.f;
      #pragma unroll
      for (int k4=0;k4<16;k4++){
        float4 z = *(const float4*)(zrow + 4*k4);
        acc = fmaf(a[jj][4*k4+0], z.x, acc);
        acc = fmaf(a[jj][4*k4+1], z.y, acc);
        acc = fmaf(a[jj][4*k4+2], z.z, acc);
        acc = fmaf(a[jj][4*k4+3], z.w, acc);
      }
      u[jj] = acc * rinv;
    }
    u[0] *= __expf(ipq.x); u[1] *= __expf(ipq.y);
    u[2] *= __expf(ipq.z); u[3] *= __expf(ipq.w);

    // next-step state
    float vm = fmaxf(fmaxf(u[0],u[1]), fmaxf(u[2],u[3]));
    vm = wave_max64(vm);
    if (l==0) wred[pw][w] = vm;
    #pragma unroll
    for (int jj=0;jj<4;jj++) Zb[pw][l][j0+jj] = u[jj];

    if (tid==0) S_arr[(size_t)b*Tt + s] = S;
    if (use_stage){
      #pragma unroll
      for (int jj=0;jj<4;jj++)
        stage[((size_t)s*Bb + b)*4096 + (size_t)(j0+jj)*64 + l] = __float2bfloat16(u[jj]);
    } else {
      #pragma unroll
      for (int jj=0;jj<4;jj++)
        out[(((size_t)s*Hh + l)*Hh + (j0+jj))*Bb + b] = __logf(u[jj]) + S;
    }
    if (s == Tt-1){
      #pragma unroll
      for (int jj=0;jj<4;jj++)
        u511[(size_t)b*4096 + (size_t)(j0+jj)*64 + l] = u[jj];
    }
    __syncthreads();
  }
}

// transpose + log: stage[s][b][j][i] bf16 -> out[s][i][j][b] f32
// grid: 512 s * 8 jb; block 256.
__global__ __launch_bounds__(256) void sohmm_emit(
    const __hip_bfloat16* __restrict__ stage, const float* __restrict__ S_arr,
    float* __restrict__ out)
{
  const int s  = blockIdx.x >> 3;
  const int jb = blockIdx.x & 7;     // 8 j per block
  const int tid = threadIdx.x;

  __shared__ unsigned short T[32*514];   // per-b row 514 ushorts (8j*64i + 2 pad), word-stride 257
  __shared__ float Sl[32];

  if (tid < 32) Sl[tid] = S_arr[(size_t)tid*Tt + s];

  const unsigned short* sg = (const unsigned short*)stage;
  #pragma unroll 4
  for (int bb=0; bb<32; bb++){
    // 512 ushorts contiguous per b
    ushort2 v = ((const ushort2*)(sg + ((size_t)s*Bb + bb)*4096 + (size_t)jb*512))[tid];
    *(ushort2*)(&T[bb*514 + tid*2]) = v;
  }
  __syncthreads();

  // 512 (i,jr) pairs; 8 pairs per round (32 b-lanes each)
  const int bch = tid & 31;
  const int pg  = tid >> 5;   // 0..7
  #pragma unroll 4
  for (int r=0; r<64; r++){
    int p  = r*8 + pg;        // 0..511
    int jr = p >> 6;          // 0..7
    int i  = p & 63;
    unsigned short h = T[bch*514 + jr*64 + i];
    float u = __uint_as_float(((unsigned)h) << 16);
    float val = __logf(u) + Sl[bch];
    out[(((size_t)s*Hh + i)*Hh + (jb*8 + jr))*Bb + bch] = val;
  }
}

__global__ __launch_bounds__(256) void sohmm_final(
    const float* __restrict__ gamma, const float* __restrict__ u511,
    const float* __restrict__ S_arr, float* __restrict__ out)
{
  const int b = blockIdx.x, tid = threadIdx.x;
  const int w = tid>>6, lane = tid&63;
  __shared__ float red[4], red2[4];

  float gm = -3.4e38f;
  #pragma unroll
  for (int q=0;q<16;q++) gm = fmaxf(gm, gamma[q*256+tid]);
  gm = wave_max64(gm);
  if (lane==0) red[w] = gm;
  __syncthreads();
  gm = fmaxf(fmaxf(red[0],red[1]), fmaxf(red[2],red[3]));
  __syncthreads();

  float se=0.f, dot=0.f;
  #pragma unroll
  for (int q=0;q<16;q++){
    int idx = q*256+tid;             // i*64+j
    int ii = idx>>6, jj = idx&63;
    float gq = __expf(gamma[idx]-gm);
    se  += gq;
    dot += gq * u511[(size_t)b*4096 + (size_t)jj*64 + ii];
  }
  #pragma unroll
  for (int off=32; off; off>>=1){
    se  += __shfl_xor(se,  off, 64);
    dot += __shfl_xor(dot, off, 64);
  }
  if (lane==0){ red[w]=se; red2[w]=dot; }
  __syncthreads();
  if (tid==0){
    float ses  = red[0]+red[1]+red[2]+red[3];
    float dots = red2[0]+red2[1]+red2[2]+red2[3];
    out[(size_t)Tt*Hh*Hh*Bb + b] = __logf(dots/ses) + S_arr[(size_t)b*Tt + (Tt-1)];
  }
}

extern "C" void kernel_launch(void* const* d_in, const int* in_sizes, int n_in,
                              void* d_out, int out_size, void* d_ws, size_t ws_size,
                              hipStream_t stream)
{
  (void)in_sizes; (void)n_in; (void)out_size;
  const float* alpha = (const float*)d_in[0];
  const float* beta  = (const float*)d_in[1];
  const float* gamma = (const float*)d_in[2];
  const int*   ids   = (const int*)d_in[3];
  float* out = (float*)d_out;
  char*  ws  = (char*)d_ws;

  float*           ipbuf = (float*)(ws + IP_OFF);
  float*           S_arr = (float*)(ws + S_OFF);
  float*           u511p = (float*)(ws + U511_OFF);
  __hip_bfloat16*  stage = (__hip_bfloat16*)(ws + STAGE_OFF);

  const int use_stage = (ws_size >= STAGE_OFF + STAGE_SZ) ? 1 : 0;

  hipLaunchKernelGGL(sohmm_scan, dim3(Bb), dim3(1024), 0, stream,
                     alpha, beta, ids, out, ipbuf, S_arr, u511p,
                     use_stage ? stage : (__hip_bfloat16*)nullptr, use_stage);
  if (use_stage){
    hipLaunchKernelGGL(sohmm_emit, dim3(Tt*8), dim3(256), 0, stream,
                       stage, S_arr, out);
  }
  hipLaunchKernelGGL(sohmm_final, dim3(Bb), dim3(256), 0, stream,
                     gamma, u511p, S_arr, out);
}

// Round 7
// 1576.261 us; speedup vs baseline: 8.2664x; 8.2664x over previous
//
#include <hip/hip_runtime.h>
#include <cstdint>
#include <cstddef>

#define Hh 64
#define Vv 32000
#define Bb 32
#define Tt 512

typedef _Float16 half2_t __attribute__((ext_vector_type(2)));

// ---- ws layout (bytes) ----
#define IP_OFF    0ull
#define IP_SZ     ((size_t)Bb*Tt*Hh*4)          // 4 MB   ip[b][t][j]
#define SL_OFF    (IP_OFF + IP_SZ)
#define SL_SZ     ((size_t)Bb*Tt*4)             // 64 KB  L[b][s]
#define U511_OFF  (SL_OFF + SL_SZ)
#define U511_SZ   ((size_t)Bb*Hh*Hh*4)          // 512 KB W511[b][j][i] f32
#define STAGE_OFF (U511_OFF + U511_SZ)
#define STAGE_SZ  ((size_t)Tt*Bb*Hh*Hh*2)       // 128 MB stage[s][b][j][i] bf16

__device__ __forceinline__ float wave_max64(float v){
  #pragma unroll
  for (int off=32; off; off>>=1) v = fmaxf(v, __shfl_xor(v, off, 64));
  return v;
}

__device__ __forceinline__ half2_t pk16(float x, float y){
  return __builtin_bit_cast(half2_t, __builtin_amdgcn_cvt_pkrtz(x, y));
}

// emissions: ip[b][t][j] = beta[j][ids[b][t]]   (grid 32*128, block 256)
__global__ __launch_bounds__(256) void sohmm_ipfill(
    const float* __restrict__ beta, const int* __restrict__ ids,
    float* __restrict__ ipbuf)
{
  const int bid = blockIdx.x;
  const int b = bid >> 7, tq = bid & 127;
  const int t = tq*4 + (threadIdx.x >> 6);
  const int j = threadIdx.x & 63;
  const int id = ids[b*Tt + t];
  ipbuf[((size_t)b*Tt + t)*Hh + j] = beta[(size_t)j*Vv + id];
}

// One WG (256 threads, 4 waves, 1 wave/SIMD -> 512 VGPR cap) per chain.
// thread (j = tid>>2, igrp = tid&3) owns outputs (i = igrp*16+m, j), m=0..15.
// alpha f16: rows m=0..12 in 416 VGPRs (half2), rows 13..15 in LDS (private stream).
__global__ __launch_bounds__(256, 1) void sohmm_scan(
    const float* __restrict__ alpha, const float* __restrict__ ipbuf,
    float* __restrict__ out, float* __restrict__ SL,
    float* __restrict__ u511, unsigned int* __restrict__ stage, int use_stage)
{
  const int b    = blockIdx.x;
  const int tid  = threadIdx.x;
  const int j    = tid >> 2;     // 0..63
  const int igrp = tid & 3;      // 0..3
  const int w    = tid >> 6;     // wave 0..3
  const int lane = tid & 63;

  // state V f16: [parity][row r][k], row stride 144 B (9 quads -> 2-way banks)
  __shared__ char zbuf[2][64*144];                 // 18,432 B
  __shared__ unsigned int aLds[256][100];          // 102,400 B (96 dw data + 4 pad; 25-dw quads)
  __shared__ float wred[2][4];

  // ---- alpha -> f16 ----
  half2_t areg[13][32];
  #pragma unroll
  for (int m=0; m<13; m++){
    const float4* ap = (const float4*)(alpha + (((size_t)(igrp*16+m))*Hh + j)*Hh);
    #pragma unroll
    for (int q=0; q<16; q++){
      float4 v = ap[q];
      areg[m][2*q+0] = pk16(v.x, v.y);
      areg[m][2*q+1] = pk16(v.z, v.w);
    }
  }
  #pragma unroll
  for (int mm=0; mm<3; mm++){
    const float4* ap = (const float4*)(alpha + (((size_t)(igrp*16+13+mm))*Hh + j)*Hh);
    #pragma unroll
    for (int q=0; q<16; q++){
      float4 v = ap[q];
      aLds[tid][mm*32+2*q+0] = __builtin_bit_cast(unsigned, __builtin_amdgcn_cvt_pkrtz(v.x, v.y));
      aLds[tid][mm*32+2*q+1] = __builtin_bit_cast(unsigned, __builtin_amdgcn_cvt_pkrtz(v.z, v.w));
    }
  }
  __syncthreads();

  float L = 0.f;

  for (int s=0; s<Tt; s++){
    const int cs = s & 1, ps = cs ^ 1;
    const int t  = (Tt-1) - s;

    float ipv = ipbuf[((size_t)b*Tt + t)*Hh + j];   // issued early, used late

    float acc[16];
    #pragma unroll
    for (int m=0;m<16;m++) acc[m] = 0.f;

    if (s){
      const char* zrow = &zbuf[ps][j*144];
      #pragma unroll
      for (int h=0; h<2; h++){
        unsigned zz[16];
        #pragma unroll
        for (int c=0; c<4; c++){
          uint4 zq = *(const uint4*)(zrow + h*64 + c*16);
          zz[4*c+0]=zq.x; zz[4*c+1]=zq.y; zz[4*c+2]=zq.z; zz[4*c+3]=zq.w;
        }
        #pragma unroll
        for (int m=0; m<13; m++){
          #pragma unroll
          for (int p=0; p<16; p++)
            acc[m] = __builtin_amdgcn_fdot2(areg[m][16*h+p],
                       __builtin_bit_cast(half2_t, zz[p]), acc[m], false);
        }
        #pragma unroll
        for (int mm=0; mm<3; mm++){
          unsigned aa[16];
          #pragma unroll
          for (int c=0; c<4; c++){
            uint4 aq = *(const uint4*)((const char*)&aLds[tid][0] + mm*128 + h*64 + c*16);
            aa[4*c+0]=aq.x; aa[4*c+1]=aq.y; aa[4*c+2]=aq.z; aa[4*c+3]=aq.w;
          }
          #pragma unroll
          for (int p=0; p<16; p++)
            acc[13+mm] = __builtin_amdgcn_fdot2(__builtin_bit_cast(half2_t, aa[p]),
                           __builtin_bit_cast(half2_t, zz[p]), acc[13+mm], false);
        }
      }
      float e = __expf(ipv);
      #pragma unroll
      for (int m=0;m<16;m++) acc[m] *= e;       // W_s
    } else {
      float e = __expf(ipv);
      #pragma unroll
      for (int m=0;m<16;m++) acc[m] = e;        // W_0 = exp(ip), same for all i
    }

    // block max -> wred[cs]
    float vm = acc[0];
    #pragma unroll
    for (int m=1;m<16;m++) vm = fmaxf(vm, acc[m]);
    vm = wave_max64(vm);
    if (lane==0) wred[cs][w] = vm;

    // L_s = L_{s-1} + log(mu_{s-1})   (wred[ps] stable since last step's mid barrier)
    if (s) L += __logf(fmaxf(fmaxf(wred[ps][0],wred[ps][1]), fmaxf(wred[ps][2],wred[ps][3])));
    if (tid==0) SL[(size_t)b*Tt + s] = L;

    // out staging: bf16(W) (emit kernel adds L and transposes), or direct fallback
    if (use_stage){
      unsigned pk8[8];
      #pragma unroll
      for (int q=0;q<8;q++)
        pk8[q] = (__float_as_uint(acc[2*q]) >> 16) | (__float_as_uint(acc[2*q+1]) & 0xFFFF0000u);
      unsigned* dst = stage + ((size_t)s*Bb + b)*2048 + (size_t)j*32 + igrp*8;
      uint4 o0; o0.x=pk8[0]; o0.y=pk8[1]; o0.z=pk8[2]; o0.w=pk8[3];
      uint4 o1; o1.x=pk8[4]; o1.y=pk8[5]; o1.z=pk8[6]; o1.w=pk8[7];
      ((uint4*)dst)[0] = o0; ((uint4*)dst)[1] = o1;
    } else {
      #pragma unroll
      for (int m=0;m<16;m++)
        out[(((size_t)s*Hh + (igrp*16+m))*Hh + j)*Bb + b] = __logf(acc[m]) + L;
    }
    if (s == Tt-1){
      float4* ud = (float4*)(u511 + (size_t)b*4096 + (size_t)j*64 + igrp*16);
      #pragma unroll
      for (int q=0;q<4;q++){
        float4 o; o.x=acc[4*q]; o.y=acc[4*q+1]; o.z=acc[4*q+2]; o.w=acc[4*q+3];
        ud[q] = o;
      }
    }

    __syncthreads();   // wred[cs] complete

    float mu   = fmaxf(fmaxf(wred[cs][0],wred[cs][1]), fmaxf(wred[cs][2],wred[cs][3]));
    float rinv = 1.0f / mu;
    {
      short* zw = (short*)(&zbuf[cs][(igrp*16)*144 + j*2]);
      #pragma unroll
      for (int m=0;m<16;m++){
        _Float16 hv = (_Float16)fmaxf(acc[m]*rinv, 1e-7f);   // clamp: no all-zero rows
        zw[m*72] = __builtin_bit_cast(short, hv);
      }
    }
    __syncthreads();   // zbuf[cs] ready for next step
  }
}

// transpose + log: stage[s][b][j][i] bf16 -> out[s][i][j][b] f32 (= log(W)+L)
__global__ __launch_bounds__(256) void sohmm_emit(
    const unsigned short* __restrict__ stage, const float* __restrict__ SL,
    float* __restrict__ out)
{
  const int s  = blockIdx.x >> 3;
  const int jb = blockIdx.x & 7;
  const int tid = threadIdx.x;

  __shared__ unsigned short T[32*514];
  __shared__ float Sl[32];

  if (tid < 32) Sl[tid] = SL[(size_t)tid*Tt + s];

  #pragma unroll 4
  for (int bb=0; bb<32; bb++){
    ushort2 v = ((const ushort2*)(stage + ((size_t)s*Bb + bb)*4096 + (size_t)jb*512))[tid];
    *(ushort2*)(&T[bb*514 + tid*2]) = v;
  }
  __syncthreads();

  const int bch = tid & 31;
  const int pg  = tid >> 5;
  #pragma unroll 4
  for (int r=0; r<64; r++){
    int p  = r*8 + pg;
    int jr = p >> 6;
    int i  = p & 63;
    unsigned short h = T[bch*514 + jr*64 + i];
    float u = __uint_as_float(((unsigned)h) << 16);
    out[(((size_t)s*Hh + i)*Hh + (jb*8 + jr))*Bb + bch] = __logf(u) + Sl[bch];
  }
}

__global__ __launch_bounds__(256) void sohmm_final(
    const float* __restrict__ gamma, const float* __restrict__ u511,
    const float* __restrict__ SL, float* __restrict__ out)
{
  const int b = blockIdx.x, tid = threadIdx.x;
  const int w = tid>>6, lane = tid&63;
  __shared__ float red[4], red2[4];

  float gm = -3.4e38f;
  #pragma unroll
  for (int q=0;q<16;q++) gm = fmaxf(gm, gamma[q*256+tid]);
  gm = wave_max64(gm);
  if (lane==0) red[w] = gm;
  __syncthreads();
  gm = fmaxf(fmaxf(red[0],red[1]), fmaxf(red[2],red[3]));
  __syncthreads();

  float se=0.f, dot=0.f;
  #pragma unroll
  for (int q=0;q<16;q++){
    int idx = q*256+tid;             // i*64+j
    int ii = idx>>6, jj = idx&63;
    float gq = __expf(gamma[idx]-gm);
    se  += gq;
    dot += gq * u511[(size_t)b*4096 + (size_t)jj*64 + ii];
  }
  #pragma unroll
  for (int off=32; off; off>>=1){
    se  += __shfl_xor(se,  off, 64);
    dot += __shfl_xor(dot, off, 64);
  }
  if (lane==0){ red[w]=se; red2[w]=dot; }
  __syncthreads();
  if (tid==0){
    float ses  = red[0]+red[1]+red[2]+red[3];
    float dots = red2[0]+red2[1]+red2[2]+red2[3];
    out[(size_t)Tt*Hh*Hh*Bb + b] = __logf(dots/ses) + SL[(size_t)b*Tt + (Tt-1)];
  }
}

extern "C" void kernel_launch(void* const* d_in, const int* in_sizes, int n_in,
                              void* d_out, int out_size, void* d_ws, size_t ws_size,
                              hipStream_t stream)
{
  (void)in_sizes; (void)n_in; (void)out_size;
  const float* alpha = (const float*)d_in[0];
  const float* beta  = (const float*)d_in[1];
  const float* gamma = (const float*)d_in[2];
  const int*   ids   = (const int*)d_in[3];
  float* out = (float*)d_out;
  char*  ws  = (char*)d_ws;

  float*          ipbuf = (float*)(ws + IP_OFF);
  float*          SLp   = (float*)(ws + SL_OFF);
  float*          u511p = (float*)(ws + U511_OFF);
  unsigned int*   stage = (unsigned int*)(ws + STAGE_OFF);

  const int use_stage = (ws_size >= STAGE_OFF + STAGE_SZ) ? 1 : 0;

  hipLaunchKernelGGL(sohmm_ipfill, dim3(Bb*128), dim3(256), 0, stream, beta, ids, ipbuf);
  hipLaunchKernelGGL(sohmm_scan, dim3(Bb), dim3(256), 0, stream,
                     alpha, ipbuf, out, SLp, u511p, stage, use_stage);
  if (use_stage){
    hipLaunchKernelGGL(sohmm_emit, dim3(Tt*8), dim3(256), 0, stream,
                       (const unsigned short*)stage, SLp, out);
  }
  hipLaunchKernelGGL(sohmm_final, dim3(Bb), dim3(256), 0, stream,
                     gamma, u511p, SLp, out);
}